// Round 1
// baseline (943.037 us; speedup 1.0000x reference)
//
#include <hip/hip_runtime.h>
#include <hip/hip_cooperative_groups.h>
#include <cstddef>

namespace cg = cooperative_groups;

#define HH 720
#define WW 1280
#define CHN 2
#define FRAME (CHN * HH * WW)   // 1,843,200
#define T_EVT 10
#define T_TOTAL 20

// Persistent device globals for the tiny scalar state (avoids d_ws entirely).
__device__ unsigned g_minkey;
__device__ unsigned g_maxkey;
__device__ unsigned g_count[T_TOTAL];

// Monotonic float<->uint key mapping (total order preserved).
__device__ __forceinline__ unsigned f2key(float f) {
    unsigned b = __float_as_uint(f);
    return b ^ ((unsigned)(((int)b) >> 31) | 0x80000000u);
}
__device__ __forceinline__ float key2f(unsigned k) {
    unsigned b = (k & 0x80000000u) ? (k ^ 0x80000000u) : ~k;
    return __uint_as_float(b);
}

__global__ void init_kernel() {
    if (threadIdx.x == 0) { g_minkey = 0xFFFFFFFFu; g_maxkey = 0u; }
    if (threadIdx.x < T_TOTAL) g_count[threadIdx.x] = 0u;
}

__global__ void minmax_kernel(const float* __restrict__ t, int n) {
    unsigned mn = 0xFFFFFFFFu, mx = 0u;
    for (int i = blockIdx.x * blockDim.x + threadIdx.x; i < n;
         i += gridDim.x * blockDim.x) {
        unsigned k = f2key(t[i]);
        mn = mn < k ? mn : k;
        mx = mx > k ? mx : k;
    }
    for (int off = 32; off > 0; off >>= 1) {
        unsigned omn = (unsigned)__shfl_down((int)mn, off, 64);
        unsigned omx = (unsigned)__shfl_down((int)mx, off, 64);
        mn = mn < omn ? mn : omn;
        mx = mx > omx ? mx : omx;
    }
    __shared__ unsigned smn[16], smx[16];
    int lane = threadIdx.x & 63, wv = threadIdx.x >> 6;
    if (lane == 0) { smn[wv] = mn; smx[wv] = mx; }
    __syncthreads();
    if (threadIdx.x == 0) {
        int nw = blockDim.x >> 6;
        for (int i = 1; i < nw; ++i) {
            mn = mn < smn[i] ? mn : smn[i];
            mx = mx > smx[i] ? mx : smx[i];
        }
        atomicMin(&g_minkey, mn);
        atomicMax(&g_maxkey, mx);
    }
}

__global__ void scatter_kernel(const int* __restrict__ x, const int* __restrict__ y,
                               const int* __restrict__ p, const float* __restrict__ t,
                               float* __restrict__ hist, int n) {
#pragma clang fp contract(off)
    int i = blockIdx.x * blockDim.x + threadIdx.x;
    if (i >= n) return;
    float tmin = key2f(g_minkey);
    float tmax = key2f(g_maxkey);
    float tv = t[i];
    float tn;
    if (tmax > tmin) {
        // exact reference op order: ((t - tmin) / denom) * (10 - 1e-6), fp32 IEEE
        tn = (tv - tmin) / (tmax - tmin) * (float)(10.0 - 1e-6);
    } else {
        tn = 0.0f;
    }
    int ti = (int)tn;                     // trunc toward zero, tn >= 0
    ti = ti < 0 ? 0 : (ti > T_EVT - 1 ? T_EVT - 1 : ti);
    int xi = x[i]; xi = xi < 0 ? 0 : (xi > WW - 1 ? WW - 1 : xi);
    int yi = y[i]; yi = yi < 0 ? 0 : (yi > HH - 1 ? HH - 1 : yi);
    int ci = p[i];                        // p in {0,1}, used directly per reference
    size_t off = (size_t)ti * FRAME + (size_t)ci * (HH * WW) + (size_t)yi * WW + xi;
    atomicAdd(hist + off, 1.0f);
}

// Cooperative scan: 256 blocks x 1024 threads, 8 pixels/thread in registers.
// hist frames live in out[(10+s)*FRAME ...]; step s consumes hist[s] before
// step 10+s overwrites that region with spikes (grid syncs enforce ordering).
__global__ __launch_bounds__(1024) void scan_kernel(float* __restrict__ out) {
#pragma clang fp contract(off)
    cg::grid_group grid = cg::this_grid();
    const float decay = (float)0.9048374180359595;  // float32(exp(-1/10))
    const int tid = blockIdx.x * 1024 + threadIdx.x;
    const int NT = 256 * 1024;                      // total threads
    float mem[8];
#pragma unroll
    for (int k = 0; k < 8; ++k) mem[k] = 0.0f;
    float thr = 1.0f;
    __shared__ unsigned wsum[16];
    const int lane = threadIdx.x & 63, wv = threadIdx.x >> 6;

    for (int s = 0; s < T_TOTAL; ++s) {
        int cnt = 0;
        const float* hist = out + (size_t)(T_EVT + s) * FRAME;
        float* o = out + (size_t)s * FRAME;
#pragma unroll
        for (int k = 0; k < 8; ++k) {
            int idx = tid + k * NT;
            if (idx < FRAME) {
                float f = (s < T_EVT) ? hist[idx] : 0.0f;
                float m = mem[k] * decay;   // contract off: separate mul, add
                m = m + f;
                float spk = (m >= thr) ? 1.0f : 0.0f;
                o[idx] = spk;
                mem[k] = m - spk * thr;
                cnt += (m >= thr) ? 1 : 0;
            }
        }
        for (int off = 32; off > 0; off >>= 1) cnt += __shfl_down(cnt, off, 64);
        if (lane == 0) wsum[wv] = (unsigned)cnt;
        __syncthreads();
        if (threadIdx.x == 0) {
            unsigned b = 0;
#pragma unroll
            for (int i = 0; i < 16; ++i) b += wsum[i];
            atomicAdd(&g_count[s], b);   // device-scope by default
        }
        grid.sync();
        unsigned total = __hip_atomic_load(&g_count[s], __ATOMIC_RELAXED,
                                           __HIP_MEMORY_SCOPE_AGENT);
        float rate = (float)total / 1843200.0f;   // exact count, one IEEE div (matches mean)
        thr = thr + 0.1f * (rate - 0.1f);
        thr = fminf(fmaxf(thr, 0.1f), 10.0f);
    }
}

extern "C" void kernel_launch(void* const* d_in, const int* in_sizes, int n_in,
                              void* d_out, int out_size, void* d_ws, size_t ws_size,
                              hipStream_t stream) {
    const int*   x = (const int*)d_in[0];
    const int*   y = (const int*)d_in[1];
    const int*   p = (const int*)d_in[2];
    const float* t = (const float*)d_in[3];
    float* out = (float*)d_out;
    const int n = in_sizes[0];

    float* hist = out + (size_t)T_EVT * FRAME;   // steps 10..19 region doubles as hist

    init_kernel<<<1, 64, 0, stream>>>();
    hipMemsetAsync((void*)hist, 0, (size_t)T_EVT * FRAME * sizeof(float), stream);
    minmax_kernel<<<512, 256, 0, stream>>>(t, n);
    scatter_kernel<<<(n + 255) / 256, 256, 0, stream>>>(x, y, p, t, hist, n);

    dim3 g(256), b(1024);
    void* args[] = { (void*)&out };
    hipLaunchCooperativeKernel((void*)scan_kernel, g, b, args, 0, stream);
}

// Round 2
// 559.219 us; speedup vs baseline: 1.6863x; 1.6863x over previous
//
#include <hip/hip_runtime.h>
#include <cstddef>

#define HH 720
#define WW 1280
#define FRAME 1843200            // 2*720*1280
#define FRAME4 460800            // FRAME/4
#define T_EVT 10
#define T_TOTAL 20
#define SCAN_BLOCKS 256
#define SCAN_THREADS 1024
#define SCAN_NT (SCAN_BLOCKS * SCAN_THREADS)   // 262144 threads
#define ARRIVE (1u << 22)        // arrival token; spike count per step < 2^22

// Persistent device globals for the tiny scalar state.
__device__ unsigned g_minkey;
__device__ unsigned g_maxkey;
__device__ unsigned g_count[T_TOTAL];   // low 22 bits: spike count; bits 22+: arrivals

// Monotonic float<->uint key mapping (total order preserved).
__device__ __forceinline__ unsigned f2key(float f) {
    unsigned b = __float_as_uint(f);
    return b ^ ((unsigned)(((int)b) >> 31) | 0x80000000u);
}
__device__ __forceinline__ float key2f(unsigned k) {
    unsigned b = (k & 0x80000000u) ? (k ^ 0x80000000u) : ~k;
    return __uint_as_float(b);
}

__global__ void init_kernel() {
    if (threadIdx.x == 0) { g_minkey = 0xFFFFFFFFu; g_maxkey = 0u; }
    if (threadIdx.x < T_TOTAL) g_count[threadIdx.x] = 0u;
}

// min/max of t, fused with zeroing the histogram region (out[10*FRAME ...]).
// Kernel boundary before scatter_kernel guarantees both are complete.
__global__ void minmax_zero_kernel(const float* __restrict__ t, int n,
                                   float4* __restrict__ hist4) {
    const int gtid = blockIdx.x * blockDim.x + threadIdx.x;
    const int gstride = gridDim.x * blockDim.x;

    // zero 10 frames = 4,608,000 float4s
    const float4 z = make_float4(0.f, 0.f, 0.f, 0.f);
    for (int i = gtid; i < T_EVT * FRAME4; i += gstride) hist4[i] = z;

    unsigned mn = 0xFFFFFFFFu, mx = 0u;
    for (int i = gtid; i < n; i += gstride) {
        unsigned k = f2key(t[i]);
        mn = mn < k ? mn : k;
        mx = mx > k ? mx : k;
    }
    for (int off = 32; off > 0; off >>= 1) {
        unsigned omn = (unsigned)__shfl_down((int)mn, off, 64);
        unsigned omx = (unsigned)__shfl_down((int)mx, off, 64);
        mn = mn < omn ? mn : omn;
        mx = mx > omx ? mx : omx;
    }
    __shared__ unsigned smn[16], smx[16];
    int lane = threadIdx.x & 63, wv = threadIdx.x >> 6;
    if (lane == 0) { smn[wv] = mn; smx[wv] = mx; }
    __syncthreads();
    if (threadIdx.x == 0) {
        int nw = blockDim.x >> 6;
        for (int i = 1; i < nw; ++i) {
            mn = mn < smn[i] ? mn : smn[i];
            mx = mx > smx[i] ? mx : smx[i];
        }
        atomicMin(&g_minkey, mn);
        atomicMax(&g_maxkey, mx);
    }
}

__global__ void scatter_kernel(const int* __restrict__ x, const int* __restrict__ y,
                               const int* __restrict__ p, const float* __restrict__ t,
                               float* __restrict__ hist, int n) {
#pragma clang fp contract(off)
    int i = blockIdx.x * blockDim.x + threadIdx.x;
    if (i >= n) return;
    float tmin = key2f(g_minkey);
    float tmax = key2f(g_maxkey);
    float tv = t[i];
    float tn;
    if (tmax > tmin) {
        // exact reference op order: ((t - tmin) / denom) * (10 - 1e-6), fp32 IEEE
        tn = (tv - tmin) / (tmax - tmin) * (float)(10.0 - 1e-6);
    } else {
        tn = 0.0f;
    }
    int ti = (int)tn;                     // trunc toward zero, tn >= 0
    ti = ti < 0 ? 0 : (ti > T_EVT - 1 ? T_EVT - 1 : ti);
    int xi = x[i]; xi = xi < 0 ? 0 : (xi > WW - 1 ? WW - 1 : xi);
    int yi = y[i]; yi = yi < 0 ? 0 : (yi > HH - 1 ? HH - 1 : yi);
    int ci = p[i];                        // p in {0,1}, used directly per reference
    size_t off = (size_t)ti * FRAME + (size_t)ci * (HH * WW) + (size_t)yi * WW + xi;
    atomicAdd(hist + off, 1.0f);
}

// Cooperative scan, float4 lanes, custom 1-atomic-per-block barrier per step.
// hist frames live in out[(10+s)*FRAME]; step s reads them at the SAME indices
// the same thread later writes spikes to at step 10+s, so no cross-thread
// visibility is needed for frame data — only the packed count atomic.
__global__ __launch_bounds__(SCAN_THREADS) void scan_kernel(float* __restrict__ out) {
#pragma clang fp contract(off)
    const float decay = (float)0.9048374180359595;  // float32(exp(-1/10))
    const int tid = blockIdx.x * SCAN_THREADS + threadIdx.x;
    const int lane = threadIdx.x & 63, wv = threadIdx.x >> 6;

    float4 mem0 = make_float4(0.f, 0.f, 0.f, 0.f);
    float4 mem1 = make_float4(0.f, 0.f, 0.f, 0.f);
    const bool has1 = (tid + SCAN_NT) < FRAME4;   // k=0 always valid (NT <= FRAME4)
    float thr = 1.0f;

    __shared__ unsigned wsum[SCAN_THREADS / 64];
    __shared__ unsigned sh_total;

    for (int s = 0; s < T_TOTAL; ++s) {
        const float4* h4 = (const float4*)(out + (size_t)(T_EVT + s) * FRAME);
        float4* o4 = (float4*)(out + (size_t)s * FRAME);
        int cnt = 0;

        {   // k = 0
            float4 f = (s < T_EVT) ? h4[tid] : make_float4(0.f, 0.f, 0.f, 0.f);
            float4 m, spk;
            m.x = mem0.x * decay; m.x = m.x + f.x;
            m.y = mem0.y * decay; m.y = m.y + f.y;
            m.z = mem0.z * decay; m.z = m.z + f.z;
            m.w = mem0.w * decay; m.w = m.w + f.w;
            spk.x = (m.x >= thr) ? 1.0f : 0.0f;
            spk.y = (m.y >= thr) ? 1.0f : 0.0f;
            spk.z = (m.z >= thr) ? 1.0f : 0.0f;
            spk.w = (m.w >= thr) ? 1.0f : 0.0f;
            o4[tid] = spk;
            mem0.x = m.x - spk.x * thr;
            mem0.y = m.y - spk.y * thr;
            mem0.z = m.z - spk.z * thr;
            mem0.w = m.w - spk.w * thr;
            cnt += (int)spk.x + (int)spk.y + (int)spk.z + (int)spk.w;
        }
        if (has1) {   // k = 1
            int i1 = tid + SCAN_NT;
            float4 f = (s < T_EVT) ? h4[i1] : make_float4(0.f, 0.f, 0.f, 0.f);
            float4 m, spk;
            m.x = mem1.x * decay; m.x = m.x + f.x;
            m.y = mem1.y * decay; m.y = m.y + f.y;
            m.z = mem1.z * decay; m.z = m.z + f.z;
            m.w = mem1.w * decay; m.w = m.w + f.w;
            spk.x = (m.x >= thr) ? 1.0f : 0.0f;
            spk.y = (m.y >= thr) ? 1.0f : 0.0f;
            spk.z = (m.z >= thr) ? 1.0f : 0.0f;
            spk.w = (m.w >= thr) ? 1.0f : 0.0f;
            o4[i1] = spk;
            mem1.x = m.x - spk.x * thr;
            mem1.y = m.y - spk.y * thr;
            mem1.z = m.z - spk.z * thr;
            mem1.w = m.w - spk.w * thr;
            cnt += (int)spk.x + (int)spk.y + (int)spk.z + (int)spk.w;
        }

        // wave reduce
        for (int off = 32; off > 0; off >>= 1) cnt += __shfl_down(cnt, off, 64);
        if (lane == 0) wsum[wv] = (unsigned)cnt;
        __syncthreads();
        if (threadIdx.x == 0) {
            unsigned b = 0;
#pragma unroll
            for (int i = 0; i < SCAN_THREADS / 64; ++i) b += wsum[i];
            // one packed atomic: count in low 22 bits, arrival token above
            __hip_atomic_fetch_add(&g_count[s], b + ARRIVE,
                                   __ATOMIC_RELAXED, __HIP_MEMORY_SCOPE_AGENT);
            unsigned v;
            do {
                __builtin_amdgcn_s_sleep(1);
                v = __hip_atomic_load(&g_count[s], __ATOMIC_RELAXED,
                                      __HIP_MEMORY_SCOPE_AGENT);
            } while ((v >> 22) != SCAN_BLOCKS);
            sh_total = v & (ARRIVE - 1u);
        }
        __syncthreads();
        float rate = (float)sh_total / 1843200.0f;  // exact count; one IEEE div = mean
        thr = thr + 0.1f * (rate - 0.1f);
        thr = fminf(fmaxf(thr, 0.1f), 10.0f);
    }
}

extern "C" void kernel_launch(void* const* d_in, const int* in_sizes, int n_in,
                              void* d_out, int out_size, void* d_ws, size_t ws_size,
                              hipStream_t stream) {
    const int*   x = (const int*)d_in[0];
    const int*   y = (const int*)d_in[1];
    const int*   p = (const int*)d_in[2];
    const float* t = (const float*)d_in[3];
    float* out = (float*)d_out;
    const int n = in_sizes[0];

    float* hist = out + (size_t)T_EVT * FRAME;   // steps 10..19 region doubles as hist

    init_kernel<<<1, 64, 0, stream>>>();
    minmax_zero_kernel<<<512, 256, 0, stream>>>(t, n, (float4*)hist);
    scatter_kernel<<<(n + 255) / 256, 256, 0, stream>>>(x, y, p, t, hist, n);

    dim3 g(SCAN_BLOCKS), b(SCAN_THREADS);
    void* args[] = { (void*)&out };
    hipLaunchCooperativeKernel((void*)scan_kernel, g, b, args, 0, stream);
}